// Round 1
// 575.121 us; speedup vs baseline: 1.0551x; 1.0551x over previous
//
#include <hip/hip_runtime.h>
#include <hip/hip_bf16.h>
#include <math.h>

#define VOCAB 50257
#define DD 512
#define H 1024
#define SS 2048
#define LL 16
#define TWO_H 2048
#define XDIM 2576   // D + 2H + L
#define YDIM 1552   // H + L + D

// ws layout (fp32 offsets)
#define OFF_V      0        // 2048 (zeroed)
#define OFF_CTX    2048     // 2048 (zeroed, contiguous with V)
#define OFF_RAW    4096     // 2048
#define OFF_SC     6144     // 2048
#define OFF_X1     8192     // 1024
#define OFF_X2     9216     // 1024
#define OFF_X3     10240    // 1024
#define OFF_G      11264    // 6144 (gi 3072 | gh 3072)
#define OFF_Y      17408    // 1552
#define OFF_LOGITS 18960    // 50257
#define OFF_PSUM   69220    // 128
#define OFF_GMAXU  69348    // 1 (unsigned monotone-encoded max)

__device__ __forceinline__ float bf2f(unsigned short s) {
  union { unsigned u; float f; } t; t.u = ((unsigned)s) << 16; return t.f;
}
__device__ __forceinline__ float bflo(unsigned w) {
  union { unsigned u; float f; } t; t.u = w << 16; return t.f;
}
__device__ __forceinline__ float bfhi(unsigned w) {
  union { unsigned u; float f; } t; t.u = w & 0xffff0000u; return t.f;
}
__device__ __forceinline__ unsigned short f2bf(float f) {
  union { float f; unsigned u; } t; t.f = f;
  unsigned r = (t.u + 0x7FFFu + ((t.u >> 16) & 1u)) >> 16;
  return (unsigned short)r;
}
template<bool BF>
__device__ __forceinline__ float ldv(const void* p, size_t i) {
  if (BF) return bf2f(((const unsigned short*)p)[i]);
  else    return ((const float*)p)[i];
}
template<bool BF>
__device__ __forceinline__ void stv(void* p, size_t i, float v) {
  if (BF) ((unsigned short*)p)[i] = f2bf(v);
  else    ((float*)p)[i] = v;
}

// monotone float<->unsigned encoding for atomicMax over signed floats
__device__ __forceinline__ unsigned enc_f(float f) {
  unsigned u = __float_as_uint(f);
  return (u & 0x80000000u) ? ~u : (u | 0x80000000u);
}
__device__ __forceinline__ float dec_f(unsigned u) {
  unsigned v = (u & 0x80000000u) ? (u & 0x7FFFFFFFu) : ~u;
  return __uint_as_float(v);
}

// block reduce: 256 threads -> 1 value (wave shuffle + 4-slot LDS)
__device__ __forceinline__ float block_reduce_256(float acc) {
  #pragma unroll
  for (int off = 32; off; off >>= 1) acc += __shfl_down(acc, off, 64);
  __shared__ float r4[4];
  if ((threadIdx.x & 63) == 0) r4[threadIdx.x >> 6] = acc;
  __syncthreads();
  return r4[0] + r4[1] + r4[2] + r4[3];
}

// ---------- init: zero v/ctx + gmax, fill y tail [nlg, emb] ----------
template<bool BF>
__global__ __launch_bounds__(256)
void init_kernel(const void* __restrict__ nlg, const void* __restrict__ embedding,
                 const int* __restrict__ token, float* __restrict__ ws) {
  int i = blockIdx.x * 256 + threadIdx.x;
  if (i < 4096) ws[OFF_V + i] = 0.f;                 // v + ctx accumulators
  if (i == 4100) *(unsigned*)(ws + OFF_GMAXU) = 0u;  // encoded -inf floor
  int j = i - 4352;
  if (j >= 0 && j < (YDIM - H)) {                    // y[H..YDIM) = [nlg, emb]
    float v;
    if (j < LL) v = ldv<BF>(nlg, j);
    else        v = ldv<BF>(embedding, (size_t)token[0] * DD + (j - LL));
    ws[OFF_Y + H + j] = v;
  }
}

// ---------- v[k] = sum_j attn_W[j][k] * h[j] ----------
template<bool BF>
__global__ __launch_bounds__(256)
void attn_v_kernel(const void* __restrict__ W, const void* __restrict__ hidden,
                   float* __restrict__ v) {
  __shared__ float hs[32];
  int j0 = blockIdx.y * 32;
  if (threadIdx.x < 32) hs[threadIdx.x] = ldv<BF>(hidden, j0 + threadIdx.x);
  __syncthreads();
  int k = blockIdx.x * 256 + threadIdx.x;
  float acc = 0.f;
  #pragma unroll 8
  for (int j = 0; j < 32; ++j)
    acc += ldv<BF>(W, (size_t)(j0 + j) * TWO_H + k) * hs[j];
  atomicAdd(&v[k], acc);
}

// ---------- generic vectorized row matvec (K % 4 == 0) ----------
template<bool BF, bool RELU>
__global__ __launch_bounds__(256)
void matvec_kernel(const void* __restrict__ W, const void* __restrict__ bias,
                   const float* __restrict__ x, float* __restrict__ out, int K) {
  int row = blockIdx.x, t = threadIdx.x;
  float acc = 0.f;
  int nc = K >> 2;
  if (BF) {
    const uint2* Wr = (const uint2*)((const unsigned short*)W + (size_t)row * K);
    for (int c = t; c < nc; c += 256) {
      uint2 u = Wr[c]; const float* xp = x + c * 4;
      acc += bflo(u.x)*xp[0] + bfhi(u.x)*xp[1] + bflo(u.y)*xp[2] + bfhi(u.y)*xp[3];
    }
  } else {
    const float4* Wr = (const float4*)((const float*)W + (size_t)row * K);
    for (int c = t; c < nc; c += 256) {
      float4 u = Wr[c]; const float* xp = x + c * 4;
      acc += u.x*xp[0] + u.y*xp[1] + u.z*xp[2] + u.w*xp[3];
    }
  }
  float s = block_reduce_256(acc);
  if (t == 0) {
    if (bias) s += ldv<BF>(bias, row);
    if (RELU) s = fmaxf(s, 0.f);
    out[row] = s;
  }
}

// ---------- softmax over 2048 raw scores (+ attn-weight output) ----------
template<bool BF>
__global__ __launch_bounds__(256)
void softmax2048_kernel(const float* __restrict__ raw, float* __restrict__ scores,
                        void* __restrict__ d_out) {
  __shared__ float red[256];
  int t = threadIdx.x;
  float m = -3.4e38f;
  for (int i = t; i < SS; i += 256) m = fmaxf(m, raw[i]);
  red[t] = m; __syncthreads();
  for (int s = 128; s; s >>= 1) { if (t < s) red[t] = fmaxf(red[t], red[t + s]); __syncthreads(); }
  float gm = red[0]; __syncthreads();
  float sum = 0.f;
  for (int i = t; i < SS; i += 256) { float e = expf(raw[i] - gm); scores[i] = e; sum += e; }
  red[t] = sum; __syncthreads();
  for (int s = 128; s; s >>= 1) { if (t < s) red[t] += red[t + s]; __syncthreads(); }
  float inv = 1.f / red[0];
  for (int i = t; i < SS; i += 256) {
    float sc = scores[i] * inv;
    scores[i] = sc;
    stv<BF>(d_out, (size_t)(VOCAB + H) + i, sc);
  }
}

// ---------- context[k] = sum_s scores[s] * enc[s][k] ----------
template<bool BF>
__global__ __launch_bounds__(256)
void context_kernel(const void* __restrict__ enc, const float* __restrict__ scores,
                    float* __restrict__ ctx) {
  __shared__ float ss[64];
  int s0 = blockIdx.y * 64;
  if (threadIdx.x < 64) ss[threadIdx.x] = scores[s0 + threadIdx.x];
  __syncthreads();
  int k = blockIdx.x * 256 + threadIdx.x;
  float acc = 0.f;
  #pragma unroll 8
  for (int s = 0; s < 64; ++s)
    acc += ss[s] * ldv<BF>(enc, (size_t)(s0 + s) * TWO_H + k);
  atomicAdd(&ctx[k], acc);
}

// ---------- comb matvec with virtual x = [emb | ctx | nlg] ----------
template<bool BF>
__global__ __launch_bounds__(256)
void comb_kernel(const void* __restrict__ W, const void* __restrict__ bias,
                 const void* __restrict__ embedding, const float* __restrict__ ctx,
                 const void* __restrict__ nlg, const int* __restrict__ token,
                 float* __restrict__ out) {
  int row = blockIdx.x, t = threadIdx.x;
  size_t ebase = (size_t)token[0] * DD;
  float acc = 0.f;
  for (int c4 = t; c4 < (XDIM >> 2); c4 += 256) {
    int c = c4 << 2;
    float x0, x1, x2, x3v;
    if (c < DD) {           // region boundaries (512, 2560) are multiples of 4
      x0 = ldv<BF>(embedding, ebase + c);     x1 = ldv<BF>(embedding, ebase + c + 1);
      x2 = ldv<BF>(embedding, ebase + c + 2); x3v = ldv<BF>(embedding, ebase + c + 3);
    } else if (c < DD + TWO_H) {
      const float* cp = ctx + (c - DD);
      x0 = cp[0]; x1 = cp[1]; x2 = cp[2]; x3v = cp[3];
    } else {
      int b = c - DD - TWO_H;
      x0 = ldv<BF>(nlg, b);     x1 = ldv<BF>(nlg, b + 1);
      x2 = ldv<BF>(nlg, b + 2); x3v = ldv<BF>(nlg, b + 3);
    }
    if (BF) {
      uint2 u = ((const uint2*)((const unsigned short*)W + (size_t)row * XDIM))[c4];
      acc += bflo(u.x)*x0 + bfhi(u.x)*x1 + bflo(u.y)*x2 + bfhi(u.y)*x3v;
    } else {
      float4 u = ((const float4*)((const float*)W + (size_t)row * XDIM))[c4];
      acc += u.x*x0 + u.y*x1 + u.z*x2 + u.w*x3v;
    }
  }
  float s = block_reduce_256(acc);
  if (t == 0) out[row] = fmaxf(s + ldv<BF>(bias, row), 0.f);
}

// ---------- fused GRU input/hidden matvecs: rows [0,3H) -> Wih.x3, [3H,6H) -> Whh.h ----------
template<bool BF>
__global__ __launch_bounds__(256)
void gru2_kernel(const void* __restrict__ Wih, const void* __restrict__ Whh,
                 const void* __restrict__ bih, const void* __restrict__ bhh,
                 const float* __restrict__ x3, const void* __restrict__ hidden,
                 float* __restrict__ g) {
  int row = blockIdx.x, t = threadIdx.x;
  bool ih = row < 3 * H;
  int r = ih ? row : row - 3 * H;
  const void* W = ih ? Wih : Whh;
  float x0, x1, x2, x3v;
  if (ih) {
    const float* xp = x3 + t * 4;
    x0 = xp[0]; x1 = xp[1]; x2 = xp[2]; x3v = xp[3];
  } else {
    x0 = ldv<BF>(hidden, 4 * t);     x1 = ldv<BF>(hidden, 4 * t + 1);
    x2 = ldv<BF>(hidden, 4 * t + 2); x3v = ldv<BF>(hidden, 4 * t + 3);
  }
  float acc;
  if (BF) {
    uint2 u = ((const uint2*)((const unsigned short*)W + (size_t)r * H))[t];
    acc = bflo(u.x)*x0 + bfhi(u.x)*x1 + bflo(u.y)*x2 + bfhi(u.y)*x3v;
  } else {
    float4 u = ((const float4*)((const float*)W + (size_t)r * H))[t];
    acc = u.x*x0 + u.y*x1 + u.z*x2 + u.w*x3v;
  }
  float s = block_reduce_256(acc);
  if (t == 0) g[row] = s + ldv<BF>(ih ? bih : bhh, r);
}

// ---------- GRU gates -> h_new into y[0..H) and d_out ----------
template<bool BF>
__global__ __launch_bounds__(256)
void gates_kernel(const float* __restrict__ g, const void* __restrict__ hidden,
                  float* __restrict__ y, void* __restrict__ d_out) {
  int i = blockIdx.x * 256 + threadIdx.x;
  if (i >= H) return;
  const float* gi = g;
  const float* gh = g + 3 * H;
  float r = 1.f / (1.f + expf(-(gi[i] + gh[i])));
  float z = 1.f / (1.f + expf(-(gi[H + i] + gh[H + i])));
  float n = tanhf(gi[2 * H + i] + r * gh[2 * H + i]);
  float hp = ldv<BF>(hidden, i);
  float hn = (1.f - z) * n + z * hp;
  y[i] = hn;
  stv<BF>(d_out, (size_t)VOCAB + i, hn);
}

// ---------- logits: 8 waves/block, 1 row/wave, fused global max ----------
template<bool BF>
__global__ __launch_bounds__(512)
void logits_kernel(const void* __restrict__ W, const void* __restrict__ bias,
                   const float* __restrict__ y, float* __restrict__ logits,
                   unsigned* __restrict__ gmaxU) {
  __shared__ float ys[YDIM];
  for (int i = threadIdx.x; i < YDIM; i += 512) ys[i] = y[i];
  __syncthreads();
  int wave = threadIdx.x >> 6, lane = threadIdx.x & 63;
  int row = blockIdx.x * 8 + wave;
  float val = -3.4e38f;
  if (row < VOCAB) {
    float acc = 0.f;
    if (BF) {
      const unsigned short* Wr = (const unsigned short*)W + (size_t)row * YDIM;
      for (int c = lane; c < (YDIM >> 3); c += 64) {     // 194 chunks of 8 bf16
        uint4 u = ((const uint4*)Wr)[c];
        const float* xp = ys + (c << 3);
        acc += bflo(u.x)*xp[0] + bfhi(u.x)*xp[1] + bflo(u.y)*xp[2] + bfhi(u.y)*xp[3]
             + bflo(u.z)*xp[4] + bfhi(u.z)*xp[5] + bflo(u.w)*xp[6] + bfhi(u.w)*xp[7];
      }
    } else {
      const float* Wr = (const float*)W + (size_t)row * YDIM;
      for (int c = lane; c < (YDIM >> 2); c += 64) {     // 388 chunks of 4 fp32
        float4 u = ((const float4*)Wr)[c];
        const float* xp = ys + (c << 2);
        acc += u.x*xp[0] + u.y*xp[1] + u.z*xp[2] + u.w*xp[3];
      }
    }
    #pragma unroll
    for (int off = 32; off; off >>= 1) acc += __shfl_down(acc, off, 64);
    if (lane == 0) {
      float lv = acc + ldv<BF>(bias, row);
      logits[row] = lv;
      val = lv;
    }
  }
  __shared__ float wmax[8];
  if (lane == 0) wmax[wave] = val;
  __syncthreads();
  if (threadIdx.x == 0) {
    float m = wmax[0];
    #pragma unroll
    for (int k = 1; k < 8; ++k) m = fmaxf(m, wmax[k]);
    atomicMax(gmaxU, enc_f(m));   // order-independent, exact
  }
}

// ---------- exp-sum partials over logits ----------
__global__ __launch_bounds__(256)
void psum_kernel(const float* __restrict__ logits, const unsigned* __restrict__ gmaxU,
                 float* __restrict__ psum) {
  float gm = dec_f(*gmaxU);
  float s = 0.f;
  for (int i = blockIdx.x * 256 + threadIdx.x; i < VOCAB; i += 128 * 256)
    s += expf(logits[i] - gm);
  float tot = block_reduce_256(s);
  if (threadIdx.x == 0) psum[blockIdx.x] = tot;
}

// ---------- writeout with inline deterministic logz ----------
template<bool BF>
__global__ __launch_bounds__(256)
void writeout_kernel(const float* __restrict__ logits, const float* __restrict__ psum,
                     const unsigned* __restrict__ gmaxU, void* __restrict__ out) {
  int t = threadIdx.x;
  float s = (t < 128) ? psum[t] : 0.f;
  float tot = block_reduce_256(s);      // deterministic: fixed 128-slot array
  __shared__ float lz;
  if (t == 0) lz = dec_f(*gmaxU) + logf(tot);
  __syncthreads();
  int i = blockIdx.x * 256 + t;
  if (i < VOCAB) stv<BF>(out, i, logits[i] - lz);
}

template<bool BF>
static void launch_all(void* const* d_in, void* d_out, float* ws, hipStream_t stream) {
  const int* token      = (const int*)d_in[0];
  const void* hidden    = d_in[1];
  const void* enc       = d_in[2];
  const void* nlg       = d_in[3];
  const void* embedding = d_in[4];
  const void* attn_W    = d_in[5];
  // d_in[6] = attn_b: (attn_b . h) constant across s => cancels in softmax
  const void* comb_W    = d_in[7];
  const void* comb_b    = d_in[8];
  const void* fc1_W     = d_in[9];
  const void* fc1_b     = d_in[10];
  const void* fc2_W     = d_in[11];
  const void* fc2_b     = d_in[12];
  const void* gru_Wih   = d_in[13];
  const void* gru_Whh   = d_in[14];
  const void* gru_bih   = d_in[15];
  const void* gru_bhh   = d_in[16];
  const void* out_W     = d_in[17];
  const void* out_b     = d_in[18];

  unsigned* gmaxU = (unsigned*)(ws + OFF_GMAXU);

  init_kernel<BF><<<20, 256, 0, stream>>>(nlg, embedding, token, ws);
  attn_v_kernel<BF><<<dim3(8, 32), 256, 0, stream>>>(attn_W, hidden, ws + OFF_V);
  matvec_kernel<BF, false><<<SS, 256, 0, stream>>>(enc, nullptr, ws + OFF_V, ws + OFF_RAW, TWO_H);
  softmax2048_kernel<BF><<<1, 256, 0, stream>>>(ws + OFF_RAW, ws + OFF_SC, d_out);
  context_kernel<BF><<<dim3(8, 32), 256, 0, stream>>>(enc, ws + OFF_SC, ws + OFF_CTX);
  comb_kernel<BF><<<H, 256, 0, stream>>>(comb_W, comb_b, embedding, ws + OFF_CTX, nlg, token, ws + OFF_X1);
  matvec_kernel<BF, true><<<H, 256, 0, stream>>>(fc1_W, fc1_b, ws + OFF_X1, ws + OFF_X2, H);
  matvec_kernel<BF, true><<<H, 256, 0, stream>>>(fc2_W, fc2_b, ws + OFF_X2, ws + OFF_X3, H);
  gru2_kernel<BF><<<6 * H, 256, 0, stream>>>(gru_Wih, gru_Whh, gru_bih, gru_bhh,
                                             ws + OFF_X3, hidden, ws + OFF_G);
  gates_kernel<BF><<<4, 256, 0, stream>>>(ws + OFF_G, hidden, ws + OFF_Y, d_out);
  logits_kernel<BF><<<(VOCAB + 7) / 8, 512, 0, stream>>>(out_W, out_b, ws + OFF_Y,
                                                         ws + OFF_LOGITS, gmaxU);
  psum_kernel<<<128, 256, 0, stream>>>(ws + OFF_LOGITS, gmaxU, ws + OFF_PSUM);
  writeout_kernel<BF><<<(VOCAB + 255) / 256, 256, 0, stream>>>(ws + OFF_LOGITS, ws + OFF_PSUM,
                                                               gmaxU, d_out);
}

extern "C" void kernel_launch(void* const* d_in, const int* in_sizes, int n_in,
                              void* d_out, int out_size, void* d_ws, size_t ws_size,
                              hipStream_t stream) {
  (void)n_in; (void)out_size; (void)ws_size;
  // Host-side dtype dispatch: embedding byte size uniquely identifies the dtype.
  // fp32: 50257*512*4 = 102,926,336 ; bf16: 50257*512*2 = 51,463,168.
  bool bf = (in_sizes && in_sizes[4] == VOCAB * DD * 2);
  float* ws = (float*)d_ws;
  if (bf) launch_all<true >(d_in, d_out, ws, stream);
  else    launch_all<false>(d_in, d_out, ws, stream);
}